// Round 1
// baseline (1773.278 us; speedup 1.0000x reference)
//
#include <hip/hip_runtime.h>
#include <hip/hip_bf16.h>

#define BB 16
#define LL 256
#define DD 256
#define DI 512
#define DS 16

// ---------------- patch embed: h[b,l,d] ----------------
__global__ void patch_embed(const float* __restrict__ x, const float* __restrict__ pw,
                            const float* __restrict__ pb, float* __restrict__ h) {
    int bl = blockIdx.x;          // b*256 + l
    int b = bl >> 8, l = bl & 255;
    int ly = l >> 4, lx = l & 15;
    __shared__ float xs[48];
    int tid = threadIdx.x;
    if (tid < 48) {
        int c = tid >> 4, py = (tid >> 2) & 3, px = tid & 3;
        xs[tid] = x[((size_t)(b * 3 + c) * 64 + ly * 4 + py) * 64 + lx * 4 + px];
    }
    __syncthreads();
    float acc = pb[tid];
#pragma unroll
    for (int k = 0; k < 48; ++k) acc += xs[k] * pw[tid * 48 + k];
    h[(size_t)bl * 256 + tid] = acc;
}

// ---------------- time embedding ----------------
__global__ void time_embed(const int* __restrict__ t, const float* __restrict__ tw1,
                           const float* __restrict__ tb1, const float* __restrict__ tw2,
                           const float* __restrict__ tb2, float* __restrict__ te) {
    int b = blockIdx.x, j = threadIdx.x;
    __shared__ float s0[256], s1[256];
    float tv = (float)t[b];
    if (j < 128) {
        float f = expf((float)j * (-9.210340371976184f / 127.f));
        float a = tv * f;
        s0[j] = sinf(a);
        s0[j + 128] = cosf(a);
    }
    __syncthreads();
    float acc = tb1[j];
    for (int k = 0; k < 256; ++k) acc += s0[k] * tw1[j * 256 + k];
    s1[j] = acc / (1.f + expf(-acc));
    __syncthreads();
    float acc2 = tb2[j];
    for (int k = 0; k < 256; ++k) acc2 += s1[k] * tw2[j * 256 + k];
    te[b * 256 + j] = acc2;
}

// ---------------- layernorm (optionally + te) ----------------
__global__ void ln_kernel(const float* __restrict__ h, const float* __restrict__ te,
                          const float* __restrict__ g, const float* __restrict__ bta,
                          float* __restrict__ out) {
    int row = blockIdx.x;         // b*L + l
    int b = row >> 8;
    int d = threadIdx.x;
    float v = h[(size_t)row * 256 + d] + (te ? te[b * 256 + d] : 0.f);
    float s = v, s2 = v * v;
#pragma unroll
    for (int o = 32; o; o >>= 1) {
        s += __shfl_down(s, o, 64);
        s2 += __shfl_down(s2, o, 64);
    }
    __shared__ float ws[4], ws2[4];
    int wid = threadIdx.x >> 6, lane = threadIdx.x & 63;
    if (lane == 0) { ws[wid] = s; ws2[wid] = s2; }
    __syncthreads();
    float mu = (ws[0] + ws[1] + ws[2] + ws[3]) * (1.f / 256.f);
    float m2 = (ws2[0] + ws2[1] + ws2[2] + ws2[3]) * (1.f / 256.f);
    float var = m2 - mu * mu;
    out[(size_t)row * 256 + d] = (v - mu) * rsqrtf(var + 1e-5f) * g[d] + bta[d];
}

// ---------------- generic fp32 GEMM: C[M,N] (+)= act(A[M,K(lda)] @ W[N,K]^T + bias) ----------------
template <int ACT, bool ADD, bool HASBIAS>
__global__ __launch_bounds__(256) void gemm_nt(const float* __restrict__ A,
                                               const float* __restrict__ W,
                                               const float* __restrict__ bias,
                                               float* __restrict__ C,
                                               int M, int N, int K, int lda) {
    __shared__ float As[16][65];
    __shared__ float Ws[16][65];
    int tx = threadIdx.x & 15, ty = threadIdx.x >> 4;
    int m0 = blockIdx.y * 64, n0 = blockIdx.x * 64;
    float acc[4][4] = {};
    for (int k0 = 0; k0 < K; k0 += 16) {
#pragma unroll
        for (int i = 0; i < 4; ++i) {
            int idx = threadIdx.x + i * 256;
            int r = idx >> 4, c = idx & 15;
            As[c][r] = A[(size_t)(m0 + r) * lda + k0 + c];
            int n = n0 + r;
            Ws[c][r] = (n < N) ? W[(size_t)n * K + k0 + c] : 0.f;
        }
        __syncthreads();
#pragma unroll
        for (int k = 0; k < 16; ++k) {
            float av[4], wv[4];
#pragma unroll
            for (int i = 0; i < 4; ++i) av[i] = As[k][ty * 4 + i];
#pragma unroll
            for (int j = 0; j < 4; ++j) wv[j] = Ws[k][tx * 4 + j];
#pragma unroll
            for (int i = 0; i < 4; ++i)
#pragma unroll
                for (int j = 0; j < 4; ++j) acc[i][j] += av[i] * wv[j];
        }
        __syncthreads();
    }
#pragma unroll
    for (int i = 0; i < 4; ++i) {
        int m = m0 + ty * 4 + i;
#pragma unroll
        for (int j = 0; j < 4; ++j) {
            int n = n0 + tx * 4 + j;
            if (n < N) {
                float v = acc[i][j];
                if (HASBIAS) v += bias[n];
                if (ACT == 1) v = (v > 20.f) ? v : log1pf(expf(v));  // softplus
                if (ADD) C[(size_t)m * N + n] += v;
                else C[(size_t)m * N + n] = v;
            }
        }
    }
}

// ---------------- causal depthwise conv (k=4) + silu ----------------
__global__ void conv_silu(const float* __restrict__ xz, const float* __restrict__ cw,
                          const float* __restrict__ cb, float* __restrict__ u) {
    int bl = blockIdx.x;          // b*L + l
    int l = bl & 255;
    int d = threadIdx.x;
    float w0 = cw[d * 4 + 0], w1 = cw[d * 4 + 1], w2 = cw[d * 4 + 2], w3 = cw[d * 4 + 3];
    const float* base = xz + (size_t)bl * 1024 + d;
    float acc = cb[d];
    if (l >= 3) acc += base[-3 * 1024] * w0;
    if (l >= 2) acc += base[-2 * 1024] * w1;
    if (l >= 1) acc += base[-1 * 1024] * w2;
    acc += base[0] * w3;
    u[(size_t)bl * 512 + d] = acc / (1.f + __expf(-acc));
}

// ---------------- SSM scan, fwd+bwd in one launch ----------------
__global__ __launch_bounds__(512) void ssm_scan(
    const float* __restrict__ u,
    const float* __restrict__ dt_f, const float* __restrict__ dt_b,
    const float* __restrict__ proj_f, const float* __restrict__ proj_b,
    const float* __restrict__ Alog_f, const float* __restrict__ Alog_b,
    const float* __restrict__ Dv_f, const float* __restrict__ Dv_b,
    float* __restrict__ yf, float* __restrict__ yb) {
    int blk = blockIdx.x;
    int b = blk >> 1, dir = blk & 1;
    const float* dt = dir ? dt_b : dt_f;
    const float* proj = dir ? proj_b : proj_f;
    const float* Alog = dir ? Alog_b : Alog_f;
    const float* Dv = dir ? Dv_b : Dv_f;
    float* y = dir ? yb : yf;
    int d = threadIdx.x;
    float A[16];
#pragma unroll
    for (int s = 0; s < 16; ++s) A[s] = -__expf(Alog[d * 16 + s]);
    float Dval = Dv[d];
    float h[16];
#pragma unroll
    for (int s = 0; s < 16; ++s) h[s] = 0.f;
    for (int ti = 0; ti < 256; ++ti) {
        int tt = dir ? (255 - ti) : ti;
        size_t row = (size_t)b * 256 + tt;
        float dtv = dt[row * 512 + d];
        float uv = u[row * 512 + d];
        const float* pr = proj + row * 64;
        float du = dtv * uv;
        float acc = 0.f;
#pragma unroll
        for (int s = 0; s < 16; ++s) {
            float a = __expf(dtv * A[s]);
            h[s] = a * h[s] + du * pr[32 + s];
            acc += h[s] * pr[48 + s];
        }
        y[row * 512 + d] = acc + uv * Dval;
    }
}

// ---------------- gate: yg = (yf+yb)*silu(z) ----------------
__global__ void gate_mul(const float* __restrict__ yf, const float* __restrict__ yb,
                         const float* __restrict__ xz, float* __restrict__ yg, int total) {
    int i = blockIdx.x * blockDim.x + threadIdx.x;
    if (i >= total) return;
    int row = i >> 9, j = i & 511;
    float z = xz[(size_t)row * 1024 + 512 + j];
    float s = z / (1.f + __expf(-z));
    yg[i] = (yf[i] + yb[i]) * s;
}

// ---------------- unpatchify ----------------
__global__ void unpatch(const float* __restrict__ tmp, float* __restrict__ out) {
    int i = blockIdx.x * blockDim.x + threadIdx.x;
    if (i >= 16 * 3 * 64 * 64) return;
    int b = i / (3 * 4096);
    int rem = i % (3 * 4096);
    int c = rem / 4096;
    int pos = rem % 4096;
    int hy = pos >> 6, wx = pos & 63;
    int l = (hy >> 2) * 16 + (wx >> 2);
    int jj = c * 16 + (hy & 3) * 4 + (wx & 3);
    out[i] = tmp[((size_t)b * 256 + l) * 48 + jj];
}

extern "C" void kernel_launch(void* const* d_in, const int* in_sizes, int n_in,
                              void* d_out, int out_size, void* d_ws, size_t ws_size,
                              hipStream_t stream) {
    const float* x        = (const float*)d_in[0];
    const int*   t        = (const int*)d_in[1];
    const float* patch_w  = (const float*)d_in[2];
    const float* patch_b  = (const float*)d_in[3];
    const float* tw1      = (const float*)d_in[4];
    const float* tb1      = (const float*)d_in[5];
    const float* tw2      = (const float*)d_in[6];
    const float* tb2      = (const float*)d_in[7];
    const float* norm_g   = (const float*)d_in[8];
    const float* norm_b   = (const float*)d_in[9];
    const float* inproj_w = (const float*)d_in[10];
    const float* conv_w   = (const float*)d_in[11];
    const float* conv_b   = (const float*)d_in[12];
    const float* Alog_f   = (const float*)d_in[13];
    const float* D_f      = (const float*)d_in[14];
    const float* xproj_f  = (const float*)d_in[15];
    const float* dtw_f    = (const float*)d_in[16];
    const float* dtb_f    = (const float*)d_in[17];
    const float* Alog_bk  = (const float*)d_in[18];
    const float* D_bk     = (const float*)d_in[19];
    const float* xproj_bk = (const float*)d_in[20];
    const float* dtw_bk   = (const float*)d_in[21];
    const float* dtb_bk   = (const float*)d_in[22];
    const float* outproj_w= (const float*)d_in[23];
    const float* fng      = (const float*)d_in[24];
    const float* fnb      = (const float*)d_in[25];
    const float* fin_w    = (const float*)d_in[26];
    const float* fin_b    = (const float*)d_in[27];
    float* out = (float*)d_out;

    float* ws = (float*)d_ws;
    float* te   = ws;                    // 4096
    float* h    = te + 4096;             // 1048576
    float* hn   = h + 1048576;           // 1048576
    float* xz   = hn + 1048576;          // 4194304
    float* u    = xz + 4194304;          // 2097152
    float* pf   = u + 2097152;           // 262144
    float* pb   = pf + 262144;           // 262144
    float* dtf  = pb + 262144;           // 2097152
    float* dtbb = dtf + 2097152;         // 2097152
    float* yf   = dtbb + 2097152;        // 2097152
    float* yb   = yf + 2097152;          // 2097152
    float* yg   = hn;                    // reuse (hn dead after inproj GEMM)

    const int M = BB * LL;               // 4096

    patch_embed<<<M, 256, 0, stream>>>(x, patch_w, patch_b, h);
    time_embed<<<BB, 256, 0, stream>>>(t, tw1, tb1, tw2, tb2, te);

    for (int i = 0; i < 4; ++i) {
        ln_kernel<<<M, 256, 0, stream>>>(h, te, norm_g + i * 256, norm_b + i * 256, hn);
        gemm_nt<0, false, false><<<dim3(16, 64), 256, 0, stream>>>(
            hn, inproj_w + (size_t)i * 1024 * 256, nullptr, xz, M, 1024, 256, 256);
        conv_silu<<<M, 512, 0, stream>>>(xz, conv_w + i * 2048, conv_b + i * 512, u);
        gemm_nt<0, false, false><<<dim3(1, 64), 256, 0, stream>>>(
            u, xproj_f + (size_t)i * 64 * 512, nullptr, pf, M, 64, 512, 512);
        gemm_nt<0, false, false><<<dim3(1, 64), 256, 0, stream>>>(
            u, xproj_bk + (size_t)i * 64 * 512, nullptr, pb, M, 64, 512, 512);
        gemm_nt<1, false, true><<<dim3(8, 64), 256, 0, stream>>>(
            pf, dtw_f + (size_t)i * 512 * 32, dtb_f + i * 512, dtf, M, 512, 32, 64);
        gemm_nt<1, false, true><<<dim3(8, 64), 256, 0, stream>>>(
            pb, dtw_bk + (size_t)i * 512 * 32, dtb_bk + i * 512, dtbb, M, 512, 32, 64);
        ssm_scan<<<32, 512, 0, stream>>>(u, dtf, dtbb, pf, pb,
                                         Alog_f + (size_t)i * 8192, Alog_bk + (size_t)i * 8192,
                                         D_f + i * 512, D_bk + i * 512, yf, yb);
        gate_mul<<<8192, 256, 0, stream>>>(yf, yb, xz, yg, 2097152);
        gemm_nt<0, true, false><<<dim3(4, 64), 256, 0, stream>>>(
            yg, outproj_w + (size_t)i * 256 * 512, nullptr, h, M, 256, 512, 512);
    }

    ln_kernel<<<M, 256, 0, stream>>>(h, nullptr, fng, fnb, hn);
    gemm_nt<0, false, true><<<dim3(1, 64), 256, 0, stream>>>(
        hn, fin_w, fin_b, pf, M, 48, 256, 256);
    unpatch<<<768, 256, 0, stream>>>(pf, out);
}

// Round 2
// 693.778 us; speedup vs baseline: 2.5560x; 2.5560x over previous
//
#include <hip/hip_runtime.h>
#include <hip/hip_bf16.h>

#define BB 16
#define LL 256
#define DD 256
#define DI 512
#define DS 16

typedef __attribute__((ext_vector_type(8))) short bf16x8;
typedef __attribute__((ext_vector_type(4))) float f32x4;

__device__ inline short f2bf(float f) {
    __hip_bfloat16 h = __float2bfloat16(f);
    return *reinterpret_cast<short*>(&h);
}

// ---------------- patch embed: h[b,l,d] ----------------
__global__ void patch_embed(const float* __restrict__ x, const float* __restrict__ pw,
                            const float* __restrict__ pb, float* __restrict__ h) {
    int bl = blockIdx.x;          // b*256 + l
    int b = bl >> 8, l = bl & 255;
    int ly = l >> 4, lx = l & 15;
    __shared__ float xs[48];
    int tid = threadIdx.x;
    if (tid < 48) {
        int c = tid >> 4, py = (tid >> 2) & 3, px = tid & 3;
        xs[tid] = x[((size_t)(b * 3 + c) * 64 + ly * 4 + py) * 64 + lx * 4 + px];
    }
    __syncthreads();
    float acc = pb[tid];
#pragma unroll
    for (int k = 0; k < 48; ++k) acc += xs[k] * pw[tid * 48 + k];
    h[(size_t)bl * 256 + tid] = acc;
}

// ---------------- time embedding ----------------
__global__ void time_embed(const int* __restrict__ t, const float* __restrict__ tw1,
                           const float* __restrict__ tb1, const float* __restrict__ tw2,
                           const float* __restrict__ tb2, float* __restrict__ te) {
    int b = blockIdx.x, j = threadIdx.x;
    __shared__ float s0[256], s1[256];
    float tv = (float)t[b];
    if (j < 128) {
        float f = expf((float)j * (-9.210340371976184f / 127.f));
        float a = tv * f;
        s0[j] = sinf(a);
        s0[j + 128] = cosf(a);
    }
    __syncthreads();
    float acc = tb1[j];
    for (int k = 0; k < 256; ++k) acc += s0[k] * tw1[j * 256 + k];
    s1[j] = acc / (1.f + expf(-acc));
    __syncthreads();
    float acc2 = tb2[j];
    for (int k = 0; k < 256; ++k) acc2 += s1[k] * tw2[j * 256 + k];
    te[b * 256 + j] = acc2;
}

// ---------------- layernorm (optionally + te) ----------------
__global__ void ln_kernel(const float* __restrict__ h, const float* __restrict__ te,
                          const float* __restrict__ g, const float* __restrict__ bta,
                          float* __restrict__ out) {
    int row = blockIdx.x;         // b*L + l
    int b = row >> 8;
    int d = threadIdx.x;
    float v = h[(size_t)row * 256 + d] + (te ? te[b * 256 + d] : 0.f);
    float s = v, s2 = v * v;
#pragma unroll
    for (int o = 32; o; o >>= 1) {
        s += __shfl_down(s, o, 64);
        s2 += __shfl_down(s2, o, 64);
    }
    __shared__ float ws[4], ws2[4];
    int wid = threadIdx.x >> 6, lane = threadIdx.x & 63;
    if (lane == 0) { ws[wid] = s; ws2[wid] = s2; }
    __syncthreads();
    float mu = (ws[0] + ws[1] + ws[2] + ws[3]) * (1.f / 256.f);
    float m2 = (ws2[0] + ws2[1] + ws2[2] + ws2[3]) * (1.f / 256.f);
    float var = m2 - mu * mu;
    out[(size_t)row * 256 + d] = (v - mu) * rsqrtf(var + 1e-5f) * g[d] + bta[d];
}

// ---------------- bf16 MFMA GEMM: C[M,N] (+)= act(A[M,K(lda)] @ W[N,K]^T + bias)
// Dual mode: block-columns with n0 >= nsplit use {A2, W2, bias2} (output col n maps to
// weight row n-nsplit). BM=128 fixed; 4 waves.
template <int BN, int WM, int WN, int FM, int FN, int ACT, bool ADD, bool HASBIAS>
__global__ __launch_bounds__(256) void gemm_mfma(
    const float* __restrict__ A, const float* __restrict__ W,
    const float* __restrict__ bias, float* __restrict__ C,
    int M, int N, int K, int lda,
    const float* __restrict__ A2, const float* __restrict__ W2,
    const float* __restrict__ bias2, int nsplit)
{
    constexpr int BM = 128;
    constexpr int LDP = 40;   // padded bf16 elems per LDS row (80 B: 2-way banks only)
    __shared__ __align__(16) short As[BM * LDP];
    __shared__ __align__(16) short Ws[BN * LDP];
    int tid = threadIdx.x;
    int lane = tid & 63;
    int w = tid >> 6;
    int wm, wn;
    if (WN == 1) { wm = w; wn = 0; } else { wm = w >> 1; wn = w & 1; }
    int m0 = blockIdx.y * BM;
    int n0 = blockIdx.x * BN;
    int wn0 = n0;
    if (nsplit > 0 && n0 >= nsplit) { A = A2; W = W2; bias = bias2; wn0 = n0 - nsplit; }

    f32x4 acc[FM][FN];
#pragma unroll
    for (int i = 0; i < FM; ++i)
#pragma unroll
        for (int j = 0; j < FN; ++j) acc[i][j] = (f32x4){0.f, 0.f, 0.f, 0.f};

    for (int k0 = 0; k0 < K; k0 += 32) {
        // stage A tile (128x32), 512 quarters of 8 floats
#pragma unroll
        for (int it = 0; it < 2; ++it) {
            int q = tid + it * 256;
            int row = q >> 2, qc = q & 3;
            const float* g = A + (size_t)(m0 + row) * lda + k0 + qc * 8;
            float4 v0 = *(const float4*)g;
            float4 v1 = *(const float4*)(g + 4);
            union { bf16x8 v; short s[8]; } u8;
            u8.s[0] = f2bf(v0.x); u8.s[1] = f2bf(v0.y); u8.s[2] = f2bf(v0.z); u8.s[3] = f2bf(v0.w);
            u8.s[4] = f2bf(v1.x); u8.s[5] = f2bf(v1.y); u8.s[6] = f2bf(v1.z); u8.s[7] = f2bf(v1.w);
            *(bf16x8*)&As[row * LDP + qc * 8] = u8.v;
        }
        // stage W tile (BNx32)
#pragma unroll
        for (int it = 0; it < BN / 64; ++it) {
            int q = tid + it * 256;
            int row = q >> 2, qc = q & 3;
            const float* g = W + (size_t)(wn0 + row) * K + k0 + qc * 8;
            float4 v0 = *(const float4*)g;
            float4 v1 = *(const float4*)(g + 4);
            union { bf16x8 v; short s[8]; } u8;
            u8.s[0] = f2bf(v0.x); u8.s[1] = f2bf(v0.y); u8.s[2] = f2bf(v0.z); u8.s[3] = f2bf(v0.w);
            u8.s[4] = f2bf(v1.x); u8.s[5] = f2bf(v1.y); u8.s[6] = f2bf(v1.z); u8.s[7] = f2bf(v1.w);
            *(bf16x8*)&Ws[row * LDP + qc * 8] = u8.v;
        }
        __syncthreads();
        int kg = lane >> 4, r = lane & 15;
        bf16x8 af[FM], bfr[FN];
#pragma unroll
        for (int i = 0; i < FM; ++i)
            af[i] = *(const bf16x8*)&As[(wm * FM * 16 + i * 16 + r) * LDP + kg * 8];
#pragma unroll
        for (int j = 0; j < FN; ++j)
            bfr[j] = *(const bf16x8*)&Ws[(wn * FN * 16 + j * 16 + r) * LDP + kg * 8];
#pragma unroll
        for (int i = 0; i < FM; ++i)
#pragma unroll
            for (int j = 0; j < FN; ++j)
                acc[i][j] = __builtin_amdgcn_mfma_f32_16x16x32_bf16(af[i], bfr[j], acc[i][j], 0, 0, 0);
        __syncthreads();
    }
    // epilogue: C row=(lane>>4)*4+reg, col=lane&15  [verified layout]
    int r = lane & 15, qg = lane >> 4;
#pragma unroll
    for (int i = 0; i < FM; ++i) {
#pragma unroll
        for (int j = 0; j < FN; ++j) {
            int col = n0 + wn * FN * 16 + j * 16 + r;
            int colw = wn0 + wn * FN * 16 + j * 16 + r;
            float bv = HASBIAS ? bias[colw] : 0.f;
#pragma unroll
            for (int q = 0; q < 4; ++q) {
                int rowm = m0 + wm * FM * 16 + i * 16 + qg * 4 + q;
                float v = acc[i][j][q] + bv;
                if (ACT == 1) v = (v > 20.f) ? v : log1pf(__expf(v));
                size_t o = (size_t)rowm * N + col;
                if (ADD) C[o] += v; else C[o] = v;
            }
        }
    }
}

// ---------------- fp32 GEMM kept for the small head ----------------
template <int ACT, bool ADD, bool HASBIAS>
__global__ __launch_bounds__(256) void gemm_nt(const float* __restrict__ A,
                                               const float* __restrict__ W,
                                               const float* __restrict__ bias,
                                               float* __restrict__ C,
                                               int M, int N, int K, int lda) {
    __shared__ float Asm[16][65];
    __shared__ float Wsm[16][65];
    int tx = threadIdx.x & 15, ty = threadIdx.x >> 4;
    int m0 = blockIdx.y * 64, n0 = blockIdx.x * 64;
    float acc[4][4] = {};
    for (int k0 = 0; k0 < K; k0 += 16) {
#pragma unroll
        for (int i = 0; i < 4; ++i) {
            int idx = threadIdx.x + i * 256;
            int rr = idx >> 4, cc = idx & 15;
            Asm[cc][rr] = A[(size_t)(m0 + rr) * lda + k0 + cc];
            int n = n0 + rr;
            Wsm[cc][rr] = (n < N) ? W[(size_t)n * K + k0 + cc] : 0.f;
        }
        __syncthreads();
#pragma unroll
        for (int k = 0; k < 16; ++k) {
            float av[4], wv[4];
#pragma unroll
            for (int i = 0; i < 4; ++i) av[i] = Asm[k][ty * 4 + i];
#pragma unroll
            for (int j = 0; j < 4; ++j) wv[j] = Wsm[k][tx * 4 + j];
#pragma unroll
            for (int i = 0; i < 4; ++i)
#pragma unroll
                for (int j = 0; j < 4; ++j) acc[i][j] += av[i] * wv[j];
        }
        __syncthreads();
    }
#pragma unroll
    for (int i = 0; i < 4; ++i) {
        int m = m0 + ty * 4 + i;
#pragma unroll
        for (int j = 0; j < 4; ++j) {
            int n = n0 + tx * 4 + j;
            if (n < N) {
                float v = acc[i][j];
                if (HASBIAS) v += bias[n];
                if (ACT == 1) v = (v > 20.f) ? v : log1pf(expf(v));
                if (ADD) C[(size_t)m * N + n] += v;
                else C[(size_t)m * N + n] = v;
            }
        }
    }
}

// ---------------- causal depthwise conv (k=4) + silu ----------------
__global__ void conv_silu(const float* __restrict__ xz, const float* __restrict__ cw,
                          const float* __restrict__ cb, float* __restrict__ u) {
    int bl = blockIdx.x;          // b*L + l
    int l = bl & 255;
    int d = threadIdx.x;
    float w0 = cw[d * 4 + 0], w1 = cw[d * 4 + 1], w2 = cw[d * 4 + 2], w3 = cw[d * 4 + 3];
    const float* base = xz + (size_t)bl * 1024 + d;
    float acc = cb[d];
    if (l >= 3) acc += base[-3 * 1024] * w0;
    if (l >= 2) acc += base[-2 * 1024] * w1;
    if (l >= 1) acc += base[-1 * 1024] * w2;
    acc += base[0] * w3;
    u[(size_t)bl * 512 + d] = acc / (1.f + __expf(-acc));
}

// ================= chunked SSM scan =================
// chunk = 16 steps, 16 chunks. proj2 layout [M][128]: cols [f: dtp32,B16,C16 | b: same].
// dt2 layout [M][1024]: cols 0-511 fwd, 512-1023 bwd. block = ((b*2+dir)*16+c).

__global__ __launch_bounds__(512) void scan_pass1(
    const float* __restrict__ u, const float* __restrict__ dt2,
    const float* __restrict__ proj2,
    const float* __restrict__ Alog_f, const float* __restrict__ Alog_b,
    float* __restrict__ P, float* __restrict__ F)
{
    int blk = blockIdx.x;
    int c = blk & 15;
    int bd = blk >> 4;
    int dir = bd & 1, b = bd >> 1;
    int d = threadIdx.x;
    const float* Alog = dir ? Alog_b : Alog_f;
    int poff = dir ? 64 : 0;
    __shared__ float Bs[16][16];
    if (threadIdx.x < 256) {
        int i = threadIdx.x >> 4, s = threadIdx.x & 15;
        int tt = dir ? 255 - (c * 16 + i) : c * 16 + i;
        Bs[i][s] = proj2[((size_t)b * 256 + tt) * 128 + poff + 32 + s];
    }
    float A[16];
#pragma unroll
    for (int s = 0; s < 16; ++s) A[s] = -__expf(Alog[d * 16 + s]);
    __syncthreads();
    float h[16];
#pragma unroll
    for (int s = 0; s < 16; ++s) h[s] = 0.f;
    float S = 0.f;
    for (int i = 0; i < 16; ++i) {
        int tt = dir ? 255 - (c * 16 + i) : c * 16 + i;
        size_t row = (size_t)b * 256 + tt;
        float dtv = dt2[row * 1024 + (dir ? 512 : 0) + d];
        float uv = u[row * 512 + d];
        S += dtv;
        float du = dtv * uv;
#pragma unroll
        for (int s = 0; s < 16; ++s) {
            float a = __expf(dtv * A[s]);
            h[s] = a * h[s] + du * Bs[i][s];
        }
    }
    size_t base = (size_t)blk * 8192 + d * 16;
#pragma unroll
    for (int s = 0; s < 16; ++s) {
        P[base + s] = __expf(A[s] * S);
        F[base + s] = h[s];
    }
}

// prefix over chunks; writes chunk-initial state Hin in-place into P
__global__ void scan_pass2(float* __restrict__ P, const float* __restrict__ F) {
    int i = blockIdx.x * blockDim.x + threadIdx.x;   // (b*2+dir)*8192 + d*16+s
    int bd = i >> 13;
    int ds = i & 8191;
    float h = 0.f;
    for (int c = 0; c < 16; ++c) {
        size_t idx = (size_t)(bd * 16 + c) * 8192 + ds;
        float p = P[idx];
        float f = F[idx];
        P[idx] = h;           // Hin for chunk c
        h = f + p * h;
    }
}

__global__ __launch_bounds__(512) void scan_pass3(
    const float* __restrict__ u, const float* __restrict__ dt2,
    const float* __restrict__ proj2,
    const float* __restrict__ Alog_f, const float* __restrict__ Alog_b,
    const float* __restrict__ Dv_f, const float* __restrict__ Dv_b,
    const float* __restrict__ Hin, float* __restrict__ y2)
{
    int blk = blockIdx.x;
    int c = blk & 15;
    int bd = blk >> 4;
    int dir = bd & 1, b = bd >> 1;
    int d = threadIdx.x;
    const float* Alog = dir ? Alog_b : Alog_f;
    int poff = dir ? 64 : 0;
    __shared__ float Bs[16][16];
    __shared__ float Cs[16][16];
    if (threadIdx.x < 256) {
        int i = threadIdx.x >> 4, s = threadIdx.x & 15;
        int tt = dir ? 255 - (c * 16 + i) : c * 16 + i;
        Bs[i][s] = proj2[((size_t)b * 256 + tt) * 128 + poff + 32 + s];
    } else {
        int i2 = (threadIdx.x - 256) >> 4, s2 = threadIdx.x & 15;
        int tt2 = dir ? 255 - (c * 16 + i2) : c * 16 + i2;
        Cs[i2][s2] = proj2[((size_t)b * 256 + tt2) * 128 + poff + 48 + s2];
    }
    float A[16];
#pragma unroll
    for (int s = 0; s < 16; ++s) A[s] = -__expf(Alog[d * 16 + s]);
    float Dval = (dir ? Dv_b : Dv_f)[d];
    __syncthreads();
    float h[16];
    size_t hbase = (size_t)blk * 8192 + d * 16;
#pragma unroll
    for (int s = 0; s < 16; ++s) h[s] = Hin[hbase + s];
    for (int i = 0; i < 16; ++i) {
        int tt = dir ? 255 - (c * 16 + i) : c * 16 + i;
        size_t row = (size_t)b * 256 + tt;
        float dtv = dt2[row * 1024 + (dir ? 512 : 0) + d];
        float uv = u[row * 512 + d];
        float du = dtv * uv;
        float acc = 0.f;
#pragma unroll
        for (int s = 0; s < 16; ++s) {
            float a = __expf(dtv * A[s]);
            h[s] = a * h[s] + du * Bs[i][s];
            acc += h[s] * Cs[i][s];
        }
        y2[row * 1024 + (dir ? 512 : 0) + d] = acc + uv * Dval;
    }
}

// ---------------- gate: yg = (yf+yb)*silu(z) ----------------
__global__ void gate_mul(const float* __restrict__ y2, const float* __restrict__ xz,
                         float* __restrict__ yg, int total) {
    int i = blockIdx.x * blockDim.x + threadIdx.x;
    if (i >= total) return;
    int row = i >> 9, j = i & 511;
    float z = xz[(size_t)row * 1024 + 512 + j];
    float s = z / (1.f + __expf(-z));
    yg[i] = (y2[(size_t)row * 1024 + j] + y2[(size_t)row * 1024 + 512 + j]) * s;
}

// ---------------- unpatchify ----------------
__global__ void unpatch(const float* __restrict__ tmp, float* __restrict__ out) {
    int i = blockIdx.x * blockDim.x + threadIdx.x;
    if (i >= 16 * 3 * 64 * 64) return;
    int b = i / (3 * 4096);
    int rem = i % (3 * 4096);
    int c = rem / 4096;
    int pos = rem % 4096;
    int hy = pos >> 6, wx = pos & 63;
    int l = (hy >> 2) * 16 + (wx >> 2);
    int jj = c * 16 + (hy & 3) * 4 + (wx & 3);
    out[i] = tmp[((size_t)b * 256 + l) * 48 + jj];
}

extern "C" void kernel_launch(void* const* d_in, const int* in_sizes, int n_in,
                              void* d_out, int out_size, void* d_ws, size_t ws_size,
                              hipStream_t stream) {
    const float* x        = (const float*)d_in[0];
    const int*   t        = (const int*)d_in[1];
    const float* patch_w  = (const float*)d_in[2];
    const float* patch_b  = (const float*)d_in[3];
    const float* tw1      = (const float*)d_in[4];
    const float* tb1      = (const float*)d_in[5];
    const float* tw2      = (const float*)d_in[6];
    const float* tb2      = (const float*)d_in[7];
    const float* norm_g   = (const float*)d_in[8];
    const float* norm_b   = (const float*)d_in[9];
    const float* inproj_w = (const float*)d_in[10];
    const float* conv_w   = (const float*)d_in[11];
    const float* conv_b   = (const float*)d_in[12];
    const float* Alog_f   = (const float*)d_in[13];
    const float* D_f      = (const float*)d_in[14];
    const float* xproj_f  = (const float*)d_in[15];
    const float* dtw_f    = (const float*)d_in[16];
    const float* dtb_f    = (const float*)d_in[17];
    const float* Alog_bk  = (const float*)d_in[18];
    const float* D_bk     = (const float*)d_in[19];
    const float* xproj_bk = (const float*)d_in[20];
    const float* dtw_bk   = (const float*)d_in[21];
    const float* dtb_bk   = (const float*)d_in[22];
    const float* outproj_w= (const float*)d_in[23];
    const float* fng      = (const float*)d_in[24];
    const float* fnb      = (const float*)d_in[25];
    const float* fin_w    = (const float*)d_in[26];
    const float* fin_b    = (const float*)d_in[27];
    float* out = (float*)d_out;

    float* ws = (float*)d_ws;
    float* te   = ws;                     // 4096
    float* h    = te + 4096;              // 1,048,576
    float* hn   = h + 1048576;            // 1,048,576
    float* xz   = hn + 1048576;           // 4,194,304
    float* u    = xz + 4194304;           // 2,097,152
    float* pf2  = u + 2097152;            // 524,288  (proj f|b, [M][128])
    float* dt2  = pf2 + 524288;           // 4,194,304 ([M][1024] f|b)
    float* y2   = dt2 + 4194304;          // 4,194,304
    float* P    = y2 + 4194304;           // 4,194,304 (decay, then Hin)
    float* F    = P + 4194304;            // 4,194,304
    float* yg   = hn;                     // reuse
    float* htmp = pf2;                    // head tmp reuse (after last layer)

    const int M = BB * LL;                // 4096

    patch_embed<<<M, 256, 0, stream>>>(x, patch_w, patch_b, h);
    time_embed<<<BB, 256, 0, stream>>>(t, tw1, tb1, tw2, tb2, te);

    for (int i = 0; i < 4; ++i) {
        ln_kernel<<<M, 256, 0, stream>>>(h, te, norm_g + i * 256, norm_b + i * 256, hn);
        // inproj: [4096,1024] = hn[4096,256] @ W^T
        gemm_mfma<128, 2, 2, 4, 4, 0, false, false><<<dim3(8, 32), 256, 0, stream>>>(
            hn, inproj_w + (size_t)i * 1024 * 256, nullptr, xz, M, 1024, 256, 256,
            nullptr, nullptr, nullptr, 0);
        conv_silu<<<M, 512, 0, stream>>>(xz, conv_w + i * 2048, conv_b + i * 512, u);
        // fused xproj f|b: [4096,128]
        gemm_mfma<64, 4, 1, 2, 4, 0, false, false><<<dim3(2, 32), 256, 0, stream>>>(
            u, xproj_f + (size_t)i * 64 * 512, nullptr, pf2, M, 128, 512, 512,
            u, xproj_bk + (size_t)i * 64 * 512, nullptr, 64);
        // fused dt f|b: [4096,1024] = softplus(proj[:, :32] @ dtw^T + dtb)
        gemm_mfma<128, 2, 2, 4, 4, 1, false, true><<<dim3(8, 32), 256, 0, stream>>>(
            pf2, dtw_f + (size_t)i * 512 * 32, dtb_f + i * 512, dt2, M, 1024, 32, 128,
            pf2 + 64, dtw_bk + (size_t)i * 512 * 32, dtb_bk + i * 512, 512);
        scan_pass1<<<512, 512, 0, stream>>>(u, dt2, pf2,
            Alog_f + (size_t)i * 8192, Alog_bk + (size_t)i * 8192, P, F);
        scan_pass2<<<1024, 256, 0, stream>>>(P, F);
        scan_pass3<<<512, 512, 0, stream>>>(u, dt2, pf2,
            Alog_f + (size_t)i * 8192, Alog_bk + (size_t)i * 8192,
            D_f + i * 512, D_bk + i * 512, P, y2);
        gate_mul<<<8192, 256, 0, stream>>>(y2, xz, yg, 2097152);
        gemm_mfma<64, 4, 1, 2, 4, 0, true, false><<<dim3(4, 32), 256, 0, stream>>>(
            yg, outproj_w + (size_t)i * 256 * 512, nullptr, h, M, 256, 512, 512,
            nullptr, nullptr, nullptr, 0);
    }

    ln_kernel<<<M, 256, 0, stream>>>(h, nullptr, fng, fnb, hn);
    gemm_nt<0, false, true><<<dim3(1, 64), 256, 0, stream>>>(
        hn, fin_w, fin_b, htmp, M, 48, 256, 256);
    unpatch<<<768, 256, 0, stream>>>(htmp, out);
}

// Round 4
// 627.925 us; speedup vs baseline: 2.8240x; 1.1049x over previous
//
#include <hip/hip_runtime.h>
#include <hip/hip_bf16.h>

#define BB 16
#define LL 256
#define DD 256
#define DI 512
#define DS 16

typedef __attribute__((ext_vector_type(8))) short bf16x8;
typedef __attribute__((ext_vector_type(4))) float f32x4;

__device__ inline short f2bf(float f) {
    __hip_bfloat16 h = __float2bfloat16(f);
    return *reinterpret_cast<short*>(&h);
}
__device__ inline float bf2f_s(short s) {
    __hip_bfloat16 h = *reinterpret_cast<__hip_bfloat16*>(&s);
    return __bfloat162float(h);
}
__device__ inline void stf(float* p, float v) { *p = v; }
__device__ inline void stf(__hip_bfloat16* p, float v) { *p = __float2bfloat16(v); }

// ---------------- patch embed: h[b,l,d], 256 blocks ----------------
__global__ __launch_bounds__(256) void patch_embed(const float* __restrict__ x,
                                                   const float* __restrict__ pw,
                                                   const float* __restrict__ pb,
                                                   float* __restrict__ h) {
    int blk = blockIdx.x;           // b*16 + lg
    int b = blk >> 4, lg = blk & 15;
    int tid = threadIdx.x;
    __shared__ float pws[48 * 258];  // transposed, padded
    __shared__ float xs[16][48];
    for (int it = 0; it < 48; ++it) {
        int idx = tid + it * 256;    // 12288 total
        float v = pw[idx];
        int dd = idx / 48, k = idx - dd * 48;
        pws[k * 258 + dd] = v;
    }
    // BUGFIX r3: 768 entries, 256 threads -> strided loop (was single guarded load)
    for (int idx = tid; idx < 16 * 48; idx += 256) {
        int li = idx / 48, k = idx - li * 48;
        int c = k >> 4, py = (k >> 2) & 3, px = k & 3;
        xs[li][k] = x[(size_t)(b * 3 + c) * 4096 + (lg * 4 + py) * 64 + li * 4 + px];
    }
    __syncthreads();
    float bv = pb[tid];
#pragma unroll 4
    for (int li = 0; li < 16; ++li) {
        float acc = bv;
#pragma unroll
        for (int k = 0; k < 48; ++k) acc += xs[li][k] * pws[k * 258 + tid];
        h[((size_t)(b * 256 + lg * 16 + li)) * 256 + tid] = acc;
    }
}

// ---------------- time embedding ----------------
__global__ void time_embed(const int* __restrict__ t, const float* __restrict__ tw1,
                           const float* __restrict__ tb1, const float* __restrict__ tw2,
                           const float* __restrict__ tb2, float* __restrict__ te) {
    int b = blockIdx.x, j = threadIdx.x;
    __shared__ float s0[256], s1[256];
    float tv = (float)t[b];
    if (j < 128) {
        float f = expf((float)j * (-9.210340371976184f / 127.f));
        float a = tv * f;
        s0[j] = sinf(a);
        s0[j + 128] = cosf(a);
    }
    __syncthreads();
    float acc = tb1[j];
    for (int k = 0; k < 256; ++k) acc += s0[k] * tw1[j * 256 + k];
    s1[j] = acc / (1.f + expf(-acc));
    __syncthreads();
    float acc2 = tb2[j];
    for (int k = 0; k < 256; ++k) acc2 += s1[k] * tw2[j * 256 + k];
    te[b * 256 + j] = acc2;
}

// ---------------- layernorm (optionally + te), templated output ----------------
template <typename TO>
__global__ void ln_kernel(const float* __restrict__ h, const float* __restrict__ te,
                          const float* __restrict__ g, const float* __restrict__ bta,
                          TO* __restrict__ out) {
    int row = blockIdx.x;         // b*L + l
    int b = row >> 8;
    int d = threadIdx.x;
    float v = h[(size_t)row * 256 + d] + (te ? te[b * 256 + d] : 0.f);
    float s = v, s2 = v * v;
#pragma unroll
    for (int o = 32; o; o >>= 1) {
        s += __shfl_down(s, o, 64);
        s2 += __shfl_down(s2, o, 64);
    }
    __shared__ float ws[4], ws2[4];
    int wid = threadIdx.x >> 6, lane = threadIdx.x & 63;
    if (lane == 0) { ws[wid] = s; ws2[wid] = s2; }
    __syncthreads();
    float mu = (ws[0] + ws[1] + ws[2] + ws[3]) * (1.f / 256.f);
    float m2 = (ws2[0] + ws2[1] + ws2[2] + ws2[3]) * (1.f / 256.f);
    float var = m2 - mu * mu;
    stf(&out[(size_t)row * 256 + d], (v - mu) * rsqrtf(var + 1e-5f) * g[d] + bta[d]);
}

// ---------------- bf16 MFMA GEMM ----------------
// C[M,N] (+)= act(A[M,K] @ W[N,K]^T + bias).  BM=128, 4 waves.
// AMODE: 0 = A bf16 (lda stride), 1 = A fp32 (lda stride), 2 = gate-fuse:
//        A = y2 bf16 [M][1024], A2 = xz bf16 [M][1024]; a[row][j] = (yf+yb)*silu(z).
// OBF: write C as bf16 (else fp32; ADD only valid with fp32).
// Dual mode (nsplit>0): block-columns with n0>=nsplit use {A2,W2,bias2}.
template <int BN, int WM, int WN, int FM, int FN, int ACT, bool ADD, bool HASBIAS,
          int AMODE, bool OBF>
__global__ __launch_bounds__(256) void gemm_mfma(
    const void* __restrict__ Ap, const float* __restrict__ W,
    const float* __restrict__ bias, void* __restrict__ Cp,
    int M, int N, int K, int lda,
    const void* __restrict__ A2p, const float* __restrict__ W2,
    const float* __restrict__ bias2, int nsplit)
{
    constexpr int BM = 128;
    constexpr int LDP = 40;   // padded bf16 elems per LDS row
    __shared__ __align__(16) short As[BM * LDP];
    __shared__ __align__(16) short Ws[BN * LDP];
    int tid = threadIdx.x;
    int lane = tid & 63;
    int w = tid >> 6;
    int wm, wn;
    if (WN == 1) { wm = w; wn = 0; } else { wm = w >> 1; wn = w & 1; }
    int m0 = blockIdx.y * BM;
    int n0 = blockIdx.x * BN;
    int wn0 = n0;
    if (nsplit > 0 && n0 >= nsplit) { Ap = A2p; W = W2; bias = bias2; wn0 = n0 - nsplit; }

    f32x4 acc[FM][FN];
#pragma unroll
    for (int i = 0; i < FM; ++i)
#pragma unroll
        for (int j = 0; j < FN; ++j) acc[i][j] = (f32x4){0.f, 0.f, 0.f, 0.f};

    for (int k0 = 0; k0 < K; k0 += 32) {
        // ---- stage A tile (128x32 bf16) ----
        if (AMODE == 0) {
#pragma unroll
            for (int it = 0; it < 2; ++it) {
                int q = tid + it * 256;
                int row = q >> 2, qc = q & 3;
                const __hip_bfloat16* g = (const __hip_bfloat16*)Ap +
                    (size_t)(m0 + row) * lda + k0 + qc * 8;
                *(bf16x8*)&As[row * LDP + qc * 8] = *(const bf16x8*)g;
            }
        } else if (AMODE == 1) {
#pragma unroll
            for (int it = 0; it < 2; ++it) {
                int q = tid + it * 256;
                int row = q >> 2, qc = q & 3;
                const float* g = (const float*)Ap + (size_t)(m0 + row) * lda + k0 + qc * 8;
                float4 v0 = *(const float4*)g;
                float4 v1 = *(const float4*)(g + 4);
                union { bf16x8 v; short s[8]; } u8;
                u8.s[0] = f2bf(v0.x); u8.s[1] = f2bf(v0.y); u8.s[2] = f2bf(v0.z); u8.s[3] = f2bf(v0.w);
                u8.s[4] = f2bf(v1.x); u8.s[5] = f2bf(v1.y); u8.s[6] = f2bf(v1.z); u8.s[7] = f2bf(v1.w);
                *(bf16x8*)&As[row * LDP + qc * 8] = u8.v;
            }
        } else {
#pragma unroll
            for (int it = 0; it < 2; ++it) {
                int q = tid + it * 256;
                int row = q >> 2, qc = q & 3;
                size_t rb = (size_t)(m0 + row) * 1024 + k0 + qc * 8;
                union { bf16x8 v; short s[8]; } uf, ub, uz, r;
                uf.v = *(const bf16x8*)((const __hip_bfloat16*)Ap + rb);
                ub.v = *(const bf16x8*)((const __hip_bfloat16*)Ap + rb + 512);
                uz.v = *(const bf16x8*)((const __hip_bfloat16*)A2p + rb + 512);
#pragma unroll
                for (int e = 0; e < 8; ++e) {
                    float z = bf2f_s(uz.s[e]);
                    float sg = z / (1.f + __expf(-z));
                    r.s[e] = f2bf((bf2f_s(uf.s[e]) + bf2f_s(ub.s[e])) * sg);
                }
                *(bf16x8*)&As[row * LDP + qc * 8] = r.v;
            }
        }
        // ---- stage W tile (BNx32, fp32 -> bf16) ----
#pragma unroll
        for (int it = 0; it < BN / 64; ++it) {
            int q = tid + it * 256;
            int row = q >> 2, qc = q & 3;
            const float* g = W + (size_t)(wn0 + row) * K + k0 + qc * 8;
            float4 v0 = *(const float4*)g;
            float4 v1 = *(const float4*)(g + 4);
            union { bf16x8 v; short s[8]; } u8;
            u8.s[0] = f2bf(v0.x); u8.s[1] = f2bf(v0.y); u8.s[2] = f2bf(v0.z); u8.s[3] = f2bf(v0.w);
            u8.s[4] = f2bf(v1.x); u8.s[5] = f2bf(v1.y); u8.s[6] = f2bf(v1.z); u8.s[7] = f2bf(v1.w);
            *(bf16x8*)&Ws[row * LDP + qc * 8] = u8.v;
        }
        __syncthreads();
        int kg = lane >> 4, r = lane & 15;
        bf16x8 af[FM], bfr[FN];
#pragma unroll
        for (int i = 0; i < FM; ++i)
            af[i] = *(const bf16x8*)&As[(wm * FM * 16 + i * 16 + r) * LDP + kg * 8];
#pragma unroll
        for (int j = 0; j < FN; ++j)
            bfr[j] = *(const bf16x8*)&Ws[(wn * FN * 16 + j * 16 + r) * LDP + kg * 8];
#pragma unroll
        for (int i = 0; i < FM; ++i)
#pragma unroll
            for (int j = 0; j < FN; ++j)
                acc[i][j] = __builtin_amdgcn_mfma_f32_16x16x32_bf16(af[i], bfr[j], acc[i][j], 0, 0, 0);
        __syncthreads();
    }
    // epilogue: C row=(lane>>4)*4+reg, col=lane&15
    int r = lane & 15, qg = lane >> 4;
#pragma unroll
    for (int i = 0; i < FM; ++i) {
#pragma unroll
        for (int j = 0; j < FN; ++j) {
            int col = n0 + wn * FN * 16 + j * 16 + r;
            int colw = wn0 + wn * FN * 16 + j * 16 + r;
            float bv = HASBIAS ? bias[colw] : 0.f;
#pragma unroll
            for (int q = 0; q < 4; ++q) {
                int rowm = m0 + wm * FM * 16 + i * 16 + qg * 4 + q;
                float v = acc[i][j][q] + bv;
                if (ACT == 1) v = (v > 20.f) ? v : log1pf(__expf(v));
                size_t o = (size_t)rowm * N + col;
                if (OBF) ((__hip_bfloat16*)Cp)[o] = __float2bfloat16(v);
                else if (ADD) ((float*)Cp)[o] += v;
                else ((float*)Cp)[o] = v;
            }
        }
    }
}

// ---------------- fp32 GEMM for the small head ----------------
template <int ACT, bool ADD, bool HASBIAS>
__global__ __launch_bounds__(256) void gemm_nt(const float* __restrict__ A,
                                               const float* __restrict__ W,
                                               const float* __restrict__ bias,
                                               float* __restrict__ C,
                                               int M, int N, int K, int lda) {
    __shared__ float Asm[16][65];
    __shared__ float Wsm[16][65];
    int tx = threadIdx.x & 15, ty = threadIdx.x >> 4;
    int m0 = blockIdx.y * 64, n0 = blockIdx.x * 64;
    float acc[4][4] = {};
    for (int k0 = 0; k0 < K; k0 += 16) {
#pragma unroll
        for (int i = 0; i < 4; ++i) {
            int idx = threadIdx.x + i * 256;
            int rr = idx >> 4, cc = idx & 15;
            Asm[cc][rr] = A[(size_t)(m0 + rr) * lda + k0 + cc];
            int n = n0 + rr;
            Wsm[cc][rr] = (n < N) ? W[(size_t)n * K + k0 + cc] : 0.f;
        }
        __syncthreads();
#pragma unroll
        for (int k = 0; k < 16; ++k) {
            float av[4], wv[4];
#pragma unroll
            for (int i = 0; i < 4; ++i) av[i] = Asm[k][ty * 4 + i];
#pragma unroll
            for (int j = 0; j < 4; ++j) wv[j] = Wsm[k][tx * 4 + j];
#pragma unroll
            for (int i = 0; i < 4; ++i)
#pragma unroll
                for (int j = 0; j < 4; ++j) acc[i][j] += av[i] * wv[j];
        }
        __syncthreads();
    }
#pragma unroll
    for (int i = 0; i < 4; ++i) {
        int m = m0 + ty * 4 + i;
#pragma unroll
        for (int j = 0; j < 4; ++j) {
            int n = n0 + tx * 4 + j;
            if (n < N) {
                float v = acc[i][j];
                if (HASBIAS) v += bias[n];
                if (ADD) C[(size_t)m * N + n] += v;
                else C[(size_t)m * N + n] = v;
            }
        }
    }
}

// ---------------- causal depthwise conv (k=4) + silu, bf16 io ----------------
__global__ void conv_silu(const __hip_bfloat16* __restrict__ xz, const float* __restrict__ cw,
                          const float* __restrict__ cb, __hip_bfloat16* __restrict__ u) {
    int bl = blockIdx.x;          // b*L + l
    int l = bl & 255;
    int d = threadIdx.x;
    float w0 = cw[d * 4 + 0], w1 = cw[d * 4 + 1], w2 = cw[d * 4 + 2], w3 = cw[d * 4 + 3];
    const __hip_bfloat16* base = xz + (size_t)bl * 1024 + d;
    float acc = cb[d];
    if (l >= 3) acc += __bfloat162float(base[-3 * 1024]) * w0;
    if (l >= 2) acc += __bfloat162float(base[-2 * 1024]) * w1;
    if (l >= 1) acc += __bfloat162float(base[-1 * 1024]) * w2;
    acc += __bfloat162float(base[0]) * w3;
    u[(size_t)bl * 512 + d] = __float2bfloat16(acc / (1.f + __expf(-acc)));
}

// ================= fused chunked SSM scan (one kernel) =================
// grid = 256: blk = ((b*2+dir)*8 + dg); 512 threads = 8 chunks x 64 channels.
// chunk = 32 steps.  LDS P/F layout [s][chunk][lane] -> all accesses lane-consecutive.
__global__ __launch_bounds__(512) void scan_fused(
    const __hip_bfloat16* __restrict__ u, const __hip_bfloat16* __restrict__ dt2,
    const float* __restrict__ pf2,
    const float* __restrict__ Alog_f, const float* __restrict__ Alog_b,
    const float* __restrict__ Dv_f, const float* __restrict__ Dv_b,
    __hip_bfloat16* __restrict__ y2)
{
    int blk = blockIdx.x;
    int dg = blk & 7;
    int bd = blk >> 3;
    int dir = bd & 1, b = bd >> 1;
    int tid = threadIdx.x;
    int dl = tid & 63, cc = tid >> 6;
    int d = dg * 64 + dl;
    int poff = dir ? 64 : 0;
    int doff = dir ? 512 : 0;
    const float* Alog = dir ? Alog_b : Alog_f;
    float Dval = (dir ? Dv_b : Dv_f)[d];

    __shared__ float Bs[256][16];
    __shared__ float Cs[256][16];
    __shared__ float Ps[16][8][64];
    __shared__ float Fs[16][8][64];

#pragma unroll
    for (int it = 0; it < 8; ++it) {
        int idx = tid + it * 512;     // 0..4095
        int i = idx >> 4, s = idx & 15;
        int tt = dir ? 255 - i : i;
        const float* pr = pf2 + ((size_t)b * 256 + tt) * 128 + poff;
        Bs[i][s] = pr[32 + s];
        Cs[i][s] = pr[48 + s];
    }
    float A[16];
#pragma unroll
    for (int s = 0; s < 16; ++s) A[s] = -__expf(Alog[d * 16 + s]);
    __syncthreads();

    float h[16];
#pragma unroll
    for (int s = 0; s < 16; ++s) h[s] = 0.f;
    float S = 0.f;
    int i0 = cc * 32;
    for (int i = i0; i < i0 + 32; ++i) {
        int tt = dir ? 255 - i : i;
        size_t row = (size_t)b * 256 + tt;
        float dtv = __bfloat162float(dt2[row * 1024 + doff + d]);
        float uv = __bfloat162float(u[row * 512 + d]);
        S += dtv;
        float du = dtv * uv;
#pragma unroll
        for (int s = 0; s < 16; ++s) {
            float a = __expf(dtv * A[s]);
            h[s] = a * h[s] + du * Bs[i][s];
        }
    }
#pragma unroll
    for (int s = 0; s < 16; ++s) {
        Ps[s][cc][dl] = __expf(A[s] * S);
        Fs[s][cc][dl] = h[s];
    }
    __syncthreads();
    // prefix over chunks: 1024 (s,dl) pairs, 2 per thread
#pragma unroll
    for (int pp = tid; pp < 1024; pp += 512) {
        int s2 = pp >> 6, dl2 = pp & 63;
        float hh = 0.f;
#pragma unroll
        for (int c2 = 0; c2 < 8; ++c2) {
            float pv = Ps[s2][c2][dl2];
            float fv = Fs[s2][c2][dl2];
            Ps[s2][c2][dl2] = hh;       // Hin for chunk c2
            hh = fv + pv * hh;
        }
    }
    __syncthreads();
#pragma unroll
    for (int s = 0; s < 16; ++s) h[s] = Ps[s][cc][dl];
    for (int i = i0; i < i0 + 32; ++i) {
        int tt = dir ? 255 - i : i;
        size_t row = (size_t)b * 256 + tt;
        float dtv = __bfloat162float(dt2[row * 1024 + doff + d]);
        float uv = __bfloat162float(u[row * 512 + d]);
        float du = dtv * uv;
        float acc = 0.f;
#pragma unroll
        for (int s = 0; s < 16; ++s) {
            float a = __expf(dtv * A[s]);
            h[s] = a * h[s] + du * Bs[i][s];
            acc += h[s] * Cs[i][s];
        }
        y2[row * 1024 + doff + d] = __float2bfloat16(acc + uv * Dval);
    }
}

// ---------------- unpatchify ----------------
__global__ void unpatch(const float* __restrict__ tmp, float* __restrict__ out) {
    int i = blockIdx.x * blockDim.x + threadIdx.x;
    if (i >= 16 * 3 * 64 * 64) return;
    int b = i / (3 * 4096);
    int rem = i % (3 * 4096);
    int c = rem / 4096;
    int pos = rem % 4096;
    int hy = pos >> 6, wx = pos & 63;
    int l = (hy >> 2) * 16 + (wx >> 2);
    int jj = c * 16 + (hy & 3) * 4 + (wx & 3);
    out[i] = tmp[((size_t)b * 256 + l) * 48 + jj];
}

extern "C" void kernel_launch(void* const* d_in, const int* in_sizes, int n_in,
                              void* d_out, int out_size, void* d_ws, size_t ws_size,
                              hipStream_t stream) {
    const float* x        = (const float*)d_in[0];
    const int*   t        = (const int*)d_in[1];
    const float* patch_w  = (const float*)d_in[2];
    const float* patch_b  = (const float*)d_in[3];
    const float* tw1      = (const float*)d_in[4];
    const float* tb1      = (const float*)d_in[5];
    const float* tw2      = (const float*)d_in[6];
    const float* tb2      = (const float*)d_in[7];
    const float* norm_g   = (const float*)d_in[8];
    const float* norm_b   = (const float*)d_in[9];
    const float* inproj_w = (const float*)d_in[10];
    const float* conv_w   = (const float*)d_in[11];
    const float* conv_b   = (const float*)d_in[12];
    const float* Alog_f   = (const float*)d_in[13];
    const float* D_f      = (const float*)d_in[14];
    const float* xproj_f  = (const float*)d_in[15];
    const float* dtw_f    = (const float*)d_in[16];
    const float* dtb_f    = (const float*)d_in[17];
    const float* Alog_bk  = (const float*)d_in[18];
    const float* D_bk     = (const float*)d_in[19];
    const float* xproj_bk = (const float*)d_in[20];
    const float* dtw_bk   = (const float*)d_in[21];
    const float* dtb_bk   = (const float*)d_in[22];
    const float* outproj_w= (const float*)d_in[23];
    const float* fng      = (const float*)d_in[24];
    const float* fnb      = (const float*)d_in[25];
    const float* fin_w    = (const float*)d_in[26];
    const float* fin_b    = (const float*)d_in[27];
    float* out = (float*)d_out;

    char* base = (char*)d_ws;
    float*          te  = (float*)base;                                   // 16 KB
    float*          h   = (float*)(base + (16UL << 10));                  // 4 MB
    __hip_bfloat16* hn  = (__hip_bfloat16*)(base + (16UL << 10) + (4UL << 20));   // 2 MB
    __hip_bfloat16* xz  = (__hip_bfloat16*)((char*)hn + (2UL << 20));     // 8 MB
    __hip_bfloat16* uu  = (__hip_bfloat16*)((char*)xz + (8UL << 20));     // 4 MB
    float*          pf2 = (float*)((char*)uu + (4UL << 20));              // 2 MB
    __hip_bfloat16* dt2 = (__hip_bfloat16*)((char*)pf2 + (2UL << 20));    // 8 MB
    __hip_bfloat16* y2  = (__hip_bfloat16*)((char*)dt2 + (8UL << 20));    // 8 MB
    float*          hnf = (float*)dt2;   // reuse after last scan (4 MB < 8 MB)
    float*          htmp= pf2;           // head tmp (768 KB < 2 MB)

    const int M = BB * LL;                // 4096

    patch_embed<<<256, 256, 0, stream>>>(x, patch_w, patch_b, h);
    time_embed<<<BB, 256, 0, stream>>>(t, tw1, tb1, tw2, tb2, te);

    for (int i = 0; i < 4; ++i) {
        ln_kernel<__hip_bfloat16><<<M, 256, 0, stream>>>(
            h, te, norm_g + i * 256, norm_b + i * 256, hn);
        // inproj: xz[4096,1024] = hn @ W^T   (bf16 out)
        gemm_mfma<128, 2, 2, 4, 4, 0, false, false, 0, true><<<dim3(8, 32), 256, 0, stream>>>(
            hn, inproj_w + (size_t)i * 1024 * 256, nullptr, xz, M, 1024, 256, 256,
            nullptr, nullptr, nullptr, 0);
        conv_silu<<<M, 512, 0, stream>>>(xz, conv_w + i * 2048, conv_b + i * 512, uu);
        // fused xproj f|b: pf2[4096,128]  (fp32 out)
        gemm_mfma<64, 4, 1, 2, 4, 0, false, false, 0, false><<<dim3(2, 32), 256, 0, stream>>>(
            uu, xproj_f + (size_t)i * 64 * 512, nullptr, pf2, M, 128, 512, 512,
            uu, xproj_bk + (size_t)i * 64 * 512, nullptr, 64);
        // fused dt f|b: dt2[4096,1024] = softplus(pf2[:, dtp] @ dtw^T + dtb)  (bf16 out)
        gemm_mfma<128, 2, 2, 4, 4, 1, false, true, 1, true><<<dim3(8, 32), 256, 0, stream>>>(
            pf2, dtw_f + (size_t)i * 512 * 32, dtb_f + i * 512, dt2, M, 1024, 32, 128,
            pf2 + 64, dtw_bk + (size_t)i * 512 * 32, dtb_bk + i * 512, 512);
        scan_fused<<<256, 512, 0, stream>>>(uu, dt2, pf2,
            Alog_f + (size_t)i * 8192, Alog_bk + (size_t)i * 8192,
            D_f + i * 512, D_bk + i * 512, y2);
        // outproj with gate fused in A-staging: h += ((yf+yb)*silu(z)) @ W^T
        gemm_mfma<64, 4, 1, 2, 4, 0, true, false, 2, false><<<dim3(4, 32), 256, 0, stream>>>(
            y2, outproj_w + (size_t)i * 256 * 512, nullptr, h, M, 256, 512, 1024,
            xz, nullptr, nullptr, 0);
    }

    ln_kernel<float><<<M, 256, 0, stream>>>(h, nullptr, fng, fnb, hnf);
    gemm_nt<0, false, true><<<dim3(1, 64), 256, 0, stream>>>(
        hnf, fin_w, fin_b, htmp, M, 48, 256, 256);
    unpatch<<<768, 256, 0, stream>>>(htmp, out);
}